// Round 1
// baseline (153.124 us; speedup 1.0000x reference)
//
#include <hip/hip_runtime.h>
#include <hip/hip_bf16.h>
#include <math.h>

// Problem constants
#define BB 8
#define NN 80
#define DD 128

__device__ __forceinline__ float pred_nl(float v) {
    const float PHI_C = 1.61803398875f;
    const float PREDS = 1.8477590650225735f; // sqrt(2 + sqrt(2))
    float raw = v - tanhf(v) * PHI_C;
    return tanhf(raw) * PREDS;
}

// ---------------------------------------------------------------------------
// Kernel A: per-node GEMVs. blockIdx.x = node*3 + mat.
// mat 0: raw_pred = state @ W1 -> prediction (with nonlinearity) -> d_out
// mat 1: keys     = state @ W2 -> k_ws
// mat 2: queries  = state @ W3 -> q_ws
// ---------------------------------------------------------------------------
__global__ __launch_bounds__(128) void k_gemv(
    const float* __restrict__ W1, const float* __restrict__ W2,
    const float* __restrict__ W3, const float* __restrict__ state,
    float* __restrict__ pred, float* __restrict__ q_ws, float* __restrict__ k_ws)
{
    int bid  = blockIdx.x;
    int node = bid / 3;          // b*NN + n
    int mat  = bid - node * 3;
    const float* W = (mat == 0 ? W1 : (mat == 1 ? W2 : W3)) + (size_t)node * DD * DD;
    const float* s = state + (size_t)node * DD;

    __shared__ __align__(16) float sv[DD];
    __shared__ float4 red[128];
    int t = threadIdx.x;
    sv[t] = s[t];
    __syncthreads();

    int jj = t >> 5;   // which j-row group (0..3)
    int kq = t & 31;   // float4 column index (k = 4*kq..4*kq+3)
    const float4* Wv = (const float4*)W;
    float4 acc = make_float4(0.f, 0.f, 0.f, 0.f);
    #pragma unroll 4
    for (int j = jj; j < DD; j += 4) {
        float4 w = Wv[j * 32 + kq];
        float sj = sv[j];
        acc.x = fmaf(sj, w.x, acc.x);
        acc.y = fmaf(sj, w.y, acc.y);
        acc.z = fmaf(sj, w.z, acc.z);
        acc.w = fmaf(sj, w.w, acc.w);
    }
    red[t] = acc;
    __syncthreads();
    if (t < 32) {
        float4 a = red[t], b4 = red[t + 32], c4 = red[t + 64], d4 = red[t + 96];
        float4 r;
        r.x = a.x + b4.x + c4.x + d4.x;
        r.y = a.y + b4.y + c4.y + d4.y;
        r.z = a.z + b4.z + c4.z + d4.z;
        r.w = a.w + b4.w + c4.w + d4.w;
        if (mat == 0) {
            float4 p;
            p.x = pred_nl(r.x); p.y = pred_nl(r.y);
            p.z = pred_nl(r.z); p.w = pred_nl(r.w);
            ((float4*)(pred + (size_t)node * DD))[t] = p;
        } else if (mat == 1) {
            ((float4*)(k_ws + (size_t)node * DD))[t] = r;
        } else {
            ((float4*)(q_ws + (size_t)node * DD))[t] = r;
        }
    }
}

// ---------------------------------------------------------------------------
// Kernel B: routing, aggregation, softmax chain -> coef. One block per node.
// ---------------------------------------------------------------------------
__global__ __launch_bounds__(128) void k_route(
    const float* __restrict__ q_ws, const float* __restrict__ k_ws,
    const float* __restrict__ A_in, const float* __restrict__ outp,
    const float* __restrict__ eye, const float* __restrict__ stomach,
    const float* __restrict__ pred, const float* __restrict__ Ebase,
    const float* __restrict__ stepc,
    float* __restrict__ target, float* __restrict__ Anew,
    float* __restrict__ EbOut, float* __restrict__ coef_ws,
    float* __restrict__ counter_out)
{
    int node = blockIdx.x;        // b*NN + n
    int b = node / NN;
    int n = node - b * NN;
    int t = threadIdx.x;
    int lane = t & 63;
    int wv = t >> 6;              // wave id (0 or 1)

    __shared__ __align__(16) float q_l[DD];
    __shared__ float raw[NN];
    __shared__ float a_l[NN];
    __shared__ int   idx5[5];
    __shared__ float p5[5];
    __shared__ float redbuf[2];

    q_l[t] = q_ws[(size_t)node * DD + t];
    __syncthreads();

    // raw_A[n,m] = dot(q_n, k_m) / sqrt(D)
    for (int m = wv; m < NN; m += 2) {
        const float* K = k_ws + (size_t)(b * NN + m) * DD;
        float p = q_l[lane] * K[lane] + q_l[lane + 64] * K[lane + 64];
        #pragma unroll
        for (int off = 32; off > 0; off >>= 1) p += __shfl_xor(p, off);
        if (lane == 0) raw[m] = p * 0.08838834764831845f; // 1/sqrt(128)
    }
    __syncthreads();

    // top-5 + softmax (serial, tiny; lax.top_k tie semantics: strict >)
    if (t == 0) {
        float vals[5]; int ids[5];
        for (int p = 0; p < 5; ++p) {
            float best = -INFINITY; int bi = 0;
            for (int m = 0; m < NN; ++m) {
                bool skip = false;
                for (int q = 0; q < p; ++q) if (ids[q] == m) skip = true;
                if (skip) continue;
                float v = raw[m];
                if (v > best) { best = v; bi = m; }
            }
            vals[p] = best; ids[p] = bi;
        }
        float mx = vals[0], s = 0.f, e[5];
        for (int p = 0; p < 5; ++p) { e[p] = expf(vals[p] - mx); s += e[p]; }
        for (int p = 0; p < 5; ++p) { p5[p] = e[p] / s; idx5[p] = ids[p]; }
    }
    __syncthreads();

    // A_new = 0.99*A + 0.01*P; rows 0,1 zeroed
    if (t < NN) {
        float P = 0.f;
        #pragma unroll
        for (int q = 0; q < 5; ++q) if (idx5[q] == t) P = p5[q];
        float a = A_in[(size_t)b * NN * NN + (size_t)n * NN + t] * 0.99f + P * 0.01f;
        if (n < 2) a = 0.f;
        a_l[t] = a;
        Anew[(size_t)b * NN * NN + (size_t)n * NN + t] = a;
    }
    __syncthreads();

    // target = A_new-weighted message aggregation (rows 0/1 -> env)
    float tg = 0.f;
    for (int m = 0; m < NN; ++m)
        tg = fmaf(a_l[m], outp[(size_t)(b * NN + m) * DD + t], tg);
    if (n == 0) tg = eye[b * DD + t];
    else if (n == 1) tg = stomach[b * DD + t];

    float err = pred[(size_t)node * DD + t] - tg;

    // softmax over D=128 (2 waves)
    float v = err;
    #pragma unroll
    for (int off = 32; off > 0; off >>= 1) v = fmaxf(v, __shfl_xor(v, off));
    if (lane == 0) redbuf[wv] = v;
    __syncthreads();
    float mx = fmaxf(redbuf[0], redbuf[1]);
    __syncthreads();          // before redbuf reuse
    float e = expf(err - mx);
    v = e;
    #pragma unroll
    for (int off = 32; off > 0; off >>= 1) v += __shfl_xor(v, off);
    if (lane == 0) redbuf[wv] = v;
    __syncthreads();
    float Ecur = e / (redbuf[0] + redbuf[1]);

    float ebin = Ebase[(size_t)node * DD + t];
    float eb0  = (ebin == 0.f) ? Ecur : ebin;
    float EbV  = 0.5f * eb0 + 0.5f * Ecur;
    float adv  = Ecur - EbV;
    float R    = -(adv * (1.0f / sqrtf(adv * adv + 1e-8f))); // rms_norm over size-1 axis
    float plast = 1.f - R;
    float maskp = (EbV > 0.f) ? 1.f : 0.f;
    float coef  = -plast * err * maskp;   // hebb[i][j] = coef_i * state_j

    target[(size_t)node * DD + t] = tg;
    EbOut [(size_t)node * DD + t] = EbV;
    coef_ws[(size_t)node * DD + t] = coef;

    if (node == 0 && t == 0) counter_out[0] = stepc[0] + 1.0f;
}

// ---------------------------------------------------------------------------
// Kernel C: elementwise weight/momentum update (rank-1 hebb, gaussian column
// mask). Grid-stride over float4 groups; 6 reads + 6 writes per element.
// ---------------------------------------------------------------------------
__global__ __launch_bounds__(256) void k_update(
    const float* __restrict__ W1, const float* __restrict__ W2,
    const float* __restrict__ W3, const float* __restrict__ M1,
    const float* __restrict__ M2, const float* __restrict__ M3,
    const float* __restrict__ state, const float* __restrict__ coef_ws,
    const float* __restrict__ stepc,
    float* __restrict__ W1n, float* __restrict__ W2n, float* __restrict__ W3n,
    float* __restrict__ M1n, float* __restrict__ M2n, float* __restrict__ M3n)
{
    __shared__ __align__(16) float g_l[DD];
    float counter = stepc[0] + 1.0f;
    float center = fmodf(counter * 1.5f, 128.0f);
    if (threadIdx.x < DD) {
        float jf = (float)threadIdx.x;
        float diff = fabsf(jf - center);
        diff = fminf(diff, 128.0f - diff);
        g_l[threadIdx.x] = expf(-(diff * diff) / 0.020001f); // 2*0.1^2 + 1e-6
    }
    __syncthreads();

    const float4* W1v = (const float4*)W1; const float4* W2v = (const float4*)W2;
    const float4* W3v = (const float4*)W3; const float4* M1v = (const float4*)M1;
    const float4* M2v = (const float4*)M2; const float4* M3v = (const float4*)M3;
    const float4* Sv  = (const float4*)state;

    const int G = BB * NN * DD * DD / 4;  // 15,728,640 float4 groups
    int tid = blockIdx.x * blockDim.x + threadIdx.x;
    int stride = gridDim.x * blockDim.x;

    for (int g = tid; g < G; g += stride) {
        int j4   = g & 31;       // float4 index within row of 128
        int row  = g >> 5;       // node*128 + i
        int node = row >> 7;
        float coef = coef_ws[row];
        float4 s4 = Sv[node * 32 + j4];
        float4 gm = ((const float4*)g_l)[j4];
        float4 w1 = W1v[g], w2 = W2v[g], w3 = W3v[g];
        float4 m1 = M1v[g], m2 = M2v[g], m3 = M3v[g];
        float4 o1, o2, o3, n1, n2, n3;
#define COMP(c)                                              \
        {                                                    \
            float hebb = coef * s4.c;                        \
            float g1 = (hebb + 0.01f * w3.c - 0.01f * w1.c) * gm.c; \
            float g2 = (hebb + 0.01f * w1.c - 0.01f * w2.c) * gm.c; \
            float g3 = (hebb + 0.01f * w2.c - 0.01f * w3.c) * gm.c; \
            n1.c = 0.42f * m1.c + 0.58f * g1;                \
            n2.c = 0.42f * m2.c + 0.58f * g2;                \
            n3.c = 0.42f * m3.c + 0.58f * g3;                \
            o1.c = w1.c + 0.001f * n1.c;                     \
            o2.c = w2.c + 0.001f * n2.c;                     \
            o3.c = w3.c + 0.001f * n3.c;                     \
        }
        COMP(x) COMP(y) COMP(z) COMP(w)
#undef COMP
        ((float4*)M1n)[g] = n1; ((float4*)M2n)[g] = n2; ((float4*)M3n)[g] = n3;
        ((float4*)W1n)[g] = o1; ((float4*)W2n)[g] = o2; ((float4*)W3n)[g] = o3;
    }
}

// ---------------------------------------------------------------------------
extern "C" void kernel_launch(void* const* d_in, const int* in_sizes, int n_in,
                              void* d_out, int out_size, void* d_ws, size_t ws_size,
                              hipStream_t stream) {
    const float* W1     = (const float*)d_in[0];
    const float* W2     = (const float*)d_in[1];
    const float* W3     = (const float*)d_in[2];
    const float* M1     = (const float*)d_in[3];
    const float* M2     = (const float*)d_in[4];
    const float* M3     = (const float*)d_in[5];
    const float* Ebase  = (const float*)d_in[6];
    const float* state  = (const float*)d_in[7];
    const float* outp   = (const float*)d_in[8];
    const float* A_in   = (const float*)d_in[9];
    const float* stepc  = (const float*)d_in[10];
    const float* eye    = (const float*)d_in[11];
    const float* stom   = (const float*)d_in[12];

    float* out = (float*)d_out;
    const int ND  = BB * NN * DD;        // 81920
    const int NA  = BB * NN * NN;        // 51200
    const int NW  = BB * NN * DD * DD;   // 10485760
    float* pred    = out;
    float* target  = out + ND;
    float* Anew    = out + 2 * ND;
    float* EbOut   = out + 2 * ND + NA;
    float* W1n     = out + 3 * ND + NA;
    float* W2n     = W1n + NW;
    float* W3n     = W2n + NW;
    float* M1n     = W3n + NW;
    float* M2n     = M1n + NW;
    float* M3n     = M2n + NW;
    float* counter_out = M3n + NW;       // final scalar

    float* ws = (float*)d_ws;
    float* q_ws    = ws;
    float* k_ws    = ws + ND;
    float* coef_ws = ws + 2 * ND;

    k_gemv<<<BB * NN * 3, 128, 0, stream>>>(W1, W2, W3, state, pred, q_ws, k_ws);
    k_route<<<BB * NN, 128, 0, stream>>>(q_ws, k_ws, A_in, outp, eye, stom,
                                         pred, Ebase, stepc,
                                         target, Anew, EbOut, coef_ws, counter_out);
    k_update<<<2048, 256, 0, stream>>>(W1, W2, W3, M1, M2, M3, state, coef_ws,
                                       stepc, W1n, W2n, W3n, M1n, M2n, M3n);
}

// Round 2
// 148.881 us; speedup vs baseline: 1.0285x; 1.0285x over previous
//
#include <hip/hip_runtime.h>
#include <hip/hip_bf16.h>
#include <math.h>

// Problem constants
#define BB 8
#define NN 80
#define DD 128

typedef float f4 __attribute__((ext_vector_type(4)));

__device__ __forceinline__ float pred_nl(float v) {
    const float PHI_C = 1.61803398875f;
    const float PREDS = 1.8477590650225735f; // sqrt(2 + sqrt(2))
    float raw = v - tanhf(v) * PHI_C;
    return tanhf(raw) * PREDS;
}

// ---------------------------------------------------------------------------
// Kernel A: per-node GEMVs. blockIdx.x = node*3 + mat.
// mat 0: raw_pred = state @ W1 -> prediction (with nonlinearity) -> d_out
// mat 1: keys     = state @ W2 -> k_ws
// mat 2: queries  = state @ W3 -> q_ws
// W loads are NORMAL (cacheable) on purpose: we want W1-3 resident in L3
// for k_update's re-read and for the next replay iteration.
// ---------------------------------------------------------------------------
__global__ __launch_bounds__(128) void k_gemv(
    const float* __restrict__ W1, const float* __restrict__ W2,
    const float* __restrict__ W3, const float* __restrict__ state,
    float* __restrict__ pred, float* __restrict__ q_ws, float* __restrict__ k_ws)
{
    int bid  = blockIdx.x;
    int node = bid / 3;          // b*NN + n
    int mat  = bid - node * 3;
    const float* W = (mat == 0 ? W1 : (mat == 1 ? W2 : W3)) + (size_t)node * DD * DD;
    const float* s = state + (size_t)node * DD;

    __shared__ __align__(16) float sv[DD];
    __shared__ f4 red[128];
    int t = threadIdx.x;
    sv[t] = s[t];
    __syncthreads();

    int jj = t >> 5;   // which j-row group (0..3)
    int kq = t & 31;   // float4 column index (k = 4*kq..4*kq+3)
    const f4* Wv = (const f4*)W;
    f4 acc = (f4)0.0f;
    #pragma unroll 4
    for (int j = jj; j < DD; j += 4) {
        f4 w = Wv[j * 32 + kq];
        float sj = sv[j];
        acc.x = fmaf(sj, w.x, acc.x);
        acc.y = fmaf(sj, w.y, acc.y);
        acc.z = fmaf(sj, w.z, acc.z);
        acc.w = fmaf(sj, w.w, acc.w);
    }
    red[t] = acc;
    __syncthreads();
    if (t < 32) {
        f4 a = red[t], b4 = red[t + 32], c4 = red[t + 64], d4 = red[t + 96];
        f4 r = a + b4 + c4 + d4;
        if (mat == 0) {
            f4 p;
            p.x = pred_nl(r.x); p.y = pred_nl(r.y);
            p.z = pred_nl(r.z); p.w = pred_nl(r.w);
            ((f4*)(pred + (size_t)node * DD))[t] = p;
        } else if (mat == 1) {
            ((f4*)(k_ws + (size_t)node * DD))[t] = r;
        } else {
            ((f4*)(q_ws + (size_t)node * DD))[t] = r;
        }
    }
}

// ---------------------------------------------------------------------------
// Kernel B: routing, aggregation, softmax chain -> coef. One block per node.
// ---------------------------------------------------------------------------
__global__ __launch_bounds__(128) void k_route(
    const float* __restrict__ q_ws, const float* __restrict__ k_ws,
    const float* __restrict__ A_in, const float* __restrict__ outp,
    const float* __restrict__ eye, const float* __restrict__ stomach,
    const float* __restrict__ pred, const float* __restrict__ Ebase,
    const float* __restrict__ stepc,
    float* __restrict__ target, float* __restrict__ Anew,
    float* __restrict__ EbOut, float* __restrict__ coef_ws,
    float* __restrict__ counter_out)
{
    int node = blockIdx.x;        // b*NN + n
    int b = node / NN;
    int n = node - b * NN;
    int t = threadIdx.x;
    int lane = t & 63;
    int wv = t >> 6;              // wave id (0 or 1)

    __shared__ __align__(16) float q_l[DD];
    __shared__ float raw[NN];
    __shared__ float a_l[NN];
    __shared__ int   idx5[5];
    __shared__ float p5[5];
    __shared__ float redbuf[2];

    q_l[t] = q_ws[(size_t)node * DD + t];
    __syncthreads();

    // raw_A[n,m] = dot(q_n, k_m) / sqrt(D)
    for (int m = wv; m < NN; m += 2) {
        const float* K = k_ws + (size_t)(b * NN + m) * DD;
        float p = q_l[lane] * K[lane] + q_l[lane + 64] * K[lane + 64];
        #pragma unroll
        for (int off = 32; off > 0; off >>= 1) p += __shfl_xor(p, off);
        if (lane == 0) raw[m] = p * 0.08838834764831845f; // 1/sqrt(128)
    }
    __syncthreads();

    // top-5 + softmax (serial, tiny; lax.top_k tie semantics: strict >)
    if (t == 0) {
        float vals[5]; int ids[5];
        for (int p = 0; p < 5; ++p) {
            float best = -INFINITY; int bi = 0;
            for (int m = 0; m < NN; ++m) {
                bool skip = false;
                for (int q = 0; q < p; ++q) if (ids[q] == m) skip = true;
                if (skip) continue;
                float v = raw[m];
                if (v > best) { best = v; bi = m; }
            }
            vals[p] = best; ids[p] = bi;
        }
        float mx = vals[0], s = 0.f, e[5];
        for (int p = 0; p < 5; ++p) { e[p] = expf(vals[p] - mx); s += e[p]; }
        for (int p = 0; p < 5; ++p) { p5[p] = e[p] / s; idx5[p] = ids[p]; }
    }
    __syncthreads();

    // A_new = 0.99*A + 0.01*P; rows 0,1 zeroed
    if (t < NN) {
        float P = 0.f;
        #pragma unroll
        for (int q = 0; q < 5; ++q) if (idx5[q] == t) P = p5[q];
        float a = A_in[(size_t)b * NN * NN + (size_t)n * NN + t] * 0.99f + P * 0.01f;
        if (n < 2) a = 0.f;
        a_l[t] = a;
        Anew[(size_t)b * NN * NN + (size_t)n * NN + t] = a;
    }
    __syncthreads();

    // target = A_new-weighted message aggregation (rows 0/1 -> env)
    float tg = 0.f;
    for (int m = 0; m < NN; ++m)
        tg = fmaf(a_l[m], outp[(size_t)(b * NN + m) * DD + t], tg);
    if (n == 0) tg = eye[b * DD + t];
    else if (n == 1) tg = stomach[b * DD + t];

    float err = pred[(size_t)node * DD + t] - tg;

    // softmax over D=128 (2 waves)
    float v = err;
    #pragma unroll
    for (int off = 32; off > 0; off >>= 1) v = fmaxf(v, __shfl_xor(v, off));
    if (lane == 0) redbuf[wv] = v;
    __syncthreads();
    float mx = fmaxf(redbuf[0], redbuf[1]);
    __syncthreads();          // before redbuf reuse
    float e = expf(err - mx);
    v = e;
    #pragma unroll
    for (int off = 32; off > 0; off >>= 1) v += __shfl_xor(v, off);
    if (lane == 0) redbuf[wv] = v;
    __syncthreads();
    float Ecur = e / (redbuf[0] + redbuf[1]);

    float ebin = Ebase[(size_t)node * DD + t];
    float eb0  = (ebin == 0.f) ? Ecur : ebin;
    float EbV  = 0.5f * eb0 + 0.5f * Ecur;
    float adv  = Ecur - EbV;
    float R    = -(adv * (1.0f / sqrtf(adv * adv + 1e-8f))); // rms_norm over size-1 axis
    float plast = 1.f - R;
    float maskp = (EbV > 0.f) ? 1.f : 0.f;
    float coef  = -plast * err * maskp;   // hebb[i][j] = coef_i * state_j

    target[(size_t)node * DD + t] = tg;
    EbOut [(size_t)node * DD + t] = EbV;
    coef_ws[(size_t)node * DD + t] = coef;

    if (node == 0 && t == 0) counter_out[0] = stepc[0] + 1.0f;
}

// ---------------------------------------------------------------------------
// Kernel C: elementwise weight/momentum update (rank-1 hebb, gaussian column
// mask). Grid-stride over float4 groups; 6 reads + 6 writes per element.
// Cache policy: W1-3 loads NORMAL (L3-resident, reused by k_gemv next replay
// and already warm from this call's k_gemv). M1-3 loads NONTEMPORAL (stream
// once). All 6 output streams NONTEMPORAL stores (write-only) -> don't evict
// W from Infinity Cache.
// ---------------------------------------------------------------------------
__global__ __launch_bounds__(256) void k_update(
    const float* __restrict__ W1, const float* __restrict__ W2,
    const float* __restrict__ W3, const float* __restrict__ M1,
    const float* __restrict__ M2, const float* __restrict__ M3,
    const float* __restrict__ state, const float* __restrict__ coef_ws,
    const float* __restrict__ stepc,
    float* __restrict__ W1n, float* __restrict__ W2n, float* __restrict__ W3n,
    float* __restrict__ M1n, float* __restrict__ M2n, float* __restrict__ M3n)
{
    __shared__ __align__(16) float g_l[DD];
    float counter = stepc[0] + 1.0f;
    float center = fmodf(counter * 1.5f, 128.0f);
    if (threadIdx.x < DD) {
        float jf = (float)threadIdx.x;
        float diff = fabsf(jf - center);
        diff = fminf(diff, 128.0f - diff);
        g_l[threadIdx.x] = expf(-(diff * diff) / 0.020001f); // 2*0.1^2 + 1e-6
    }
    __syncthreads();

    const f4* W1v = (const f4*)W1; const f4* W2v = (const f4*)W2;
    const f4* W3v = (const f4*)W3; const f4* M1v = (const f4*)M1;
    const f4* M2v = (const f4*)M2; const f4* M3v = (const f4*)M3;
    const f4* Sv  = (const f4*)state;

    const int G = BB * NN * DD * DD / 4;  // 15,728,640 float4 groups
    int tid = blockIdx.x * blockDim.x + threadIdx.x;
    int stride = gridDim.x * blockDim.x;

    for (int g = tid; g < G; g += stride) {
        int j4   = g & 31;       // float4 index within row of 128
        int row  = g >> 5;       // node*128 + i
        int node = row >> 7;
        float coef = coef_ws[row];
        f4 s4 = Sv[node * 32 + j4];
        f4 gm = ((const f4*)g_l)[j4];
        f4 w1 = W1v[g], w2 = W2v[g], w3 = W3v[g];
        f4 m1 = __builtin_nontemporal_load(M1v + g);
        f4 m2 = __builtin_nontemporal_load(M2v + g);
        f4 m3 = __builtin_nontemporal_load(M3v + g);
        f4 o1, o2, o3, n1, n2, n3;
#define COMP(c)                                              \
        {                                                    \
            float hebb = coef * s4.c;                        \
            float g1 = (hebb + 0.01f * w3.c - 0.01f * w1.c) * gm.c; \
            float g2 = (hebb + 0.01f * w1.c - 0.01f * w2.c) * gm.c; \
            float g3 = (hebb + 0.01f * w2.c - 0.01f * w3.c) * gm.c; \
            n1.c = 0.42f * m1.c + 0.58f * g1;                \
            n2.c = 0.42f * m2.c + 0.58f * g2;                \
            n3.c = 0.42f * m3.c + 0.58f * g3;                \
            o1.c = w1.c + 0.001f * n1.c;                     \
            o2.c = w2.c + 0.001f * n2.c;                     \
            o3.c = w3.c + 0.001f * n3.c;                     \
        }
        COMP(x) COMP(y) COMP(z) COMP(w)
#undef COMP
        __builtin_nontemporal_store(n1, (f4*)M1n + g);
        __builtin_nontemporal_store(n2, (f4*)M2n + g);
        __builtin_nontemporal_store(n3, (f4*)M3n + g);
        __builtin_nontemporal_store(o1, (f4*)W1n + g);
        __builtin_nontemporal_store(o2, (f4*)W2n + g);
        __builtin_nontemporal_store(o3, (f4*)W3n + g);
    }
}

// ---------------------------------------------------------------------------
extern "C" void kernel_launch(void* const* d_in, const int* in_sizes, int n_in,
                              void* d_out, int out_size, void* d_ws, size_t ws_size,
                              hipStream_t stream) {
    const float* W1     = (const float*)d_in[0];
    const float* W2     = (const float*)d_in[1];
    const float* W3     = (const float*)d_in[2];
    const float* M1     = (const float*)d_in[3];
    const float* M2     = (const float*)d_in[4];
    const float* M3     = (const float*)d_in[5];
    const float* Ebase  = (const float*)d_in[6];
    const float* state  = (const float*)d_in[7];
    const float* outp   = (const float*)d_in[8];
    const float* A_in   = (const float*)d_in[9];
    const float* stepc  = (const float*)d_in[10];
    const float* eye    = (const float*)d_in[11];
    const float* stom   = (const float*)d_in[12];

    float* out = (float*)d_out;
    const int ND  = BB * NN * DD;        // 81920
    const int NA  = BB * NN * NN;        // 51200
    const int NW  = BB * NN * DD * DD;   // 10485760
    float* pred    = out;
    float* target  = out + ND;
    float* Anew    = out + 2 * ND;
    float* EbOut   = out + 2 * ND + NA;
    float* W1n     = out + 3 * ND + NA;
    float* W2n     = W1n + NW;
    float* W3n     = W2n + NW;
    float* M1n     = W3n + NW;
    float* M2n     = M1n + NW;
    float* M3n     = M2n + NW;
    float* counter_out = M3n + NW;       // final scalar

    float* ws = (float*)d_ws;
    float* q_ws    = ws;
    float* k_ws    = ws + ND;
    float* coef_ws = ws + 2 * ND;

    k_gemv<<<BB * NN * 3, 128, 0, stream>>>(W1, W2, W3, state, pred, q_ws, k_ws);
    k_route<<<BB * NN, 128, 0, stream>>>(q_ws, k_ws, A_in, outp, eye, stom,
                                         pred, Ebase, stepc,
                                         target, Anew, EbOut, coef_ws, counter_out);
    k_update<<<2048, 256, 0, stream>>>(W1, W2, W3, M1, M2, M3, state, coef_ws,
                                       stepc, W1n, W2n, W3n, M1n, M2n, M3n);
}